// Round 1
// 366.601 us; speedup vs baseline: 1.0171x; 1.0171x over previous
//
#include <hip/hip_runtime.h>

typedef __attribute__((ext_vector_type(8))) short s8v;
typedef __attribute__((ext_vector_type(4))) short s4v;
typedef __attribute__((ext_vector_type(4))) float f4v;

#define DIM 2048
#define NROW 512   // 2*B
#define NB 256     // B

__device__ inline short f2bf(float f) {
    union { float f; unsigned int u; } v; v.f = f;
    unsigned int u = v.u;
    unsigned int r = (u + 0x7fffu + ((u >> 16) & 1u)) >> 16;
    return (short)r;
}

// pack two floats -> two truncated bf16 in one int (v_perm_b32).
// D.bytes = [a.b2, a.b3, b.b2, b.b3]  => low short = bf16(a), high short = bf16(b)
__device__ __forceinline__ int pk_trunc(float a, float b) {
    return __builtin_amdgcn_perm(__float_as_uint(b), __float_as_uint(a), 0x07060302);
}

// sum across a quad of lanes via DPP quad_perm (VALU only, no LDS pipe)
__device__ __forceinline__ float qsum(float s) {
    int i = __float_as_int(s);
    s += __int_as_float(__builtin_amdgcn_update_dpp(i, i, 0xB1, 0xF, 0xF, false)); // [1,0,3,2]
    i = __float_as_int(s);
    s += __int_as_float(__builtin_amdgcn_update_dpp(i, i, 0x4E, 0xF, 0xF, false)); // [2,3,0,1]
    return s;
}

// ---- 1. spatial mean pool, latency-optimized ----
// 8192 single-shot blocks x 32 KB. 4 lanes per (row,dim) pair: each lane reads
// 8 contiguous float4 (quad covers full 64B lines per instruction), reduces
// lane-locally, then 2 DPP quad-perm adds. No ds_swizzle, no pipeline to
// collapse: 8 loads in flight per thread, ~45 VGPR -> 8 waves/SIMD.
__global__ __launch_bounds__(256) void pool_kernel(const float* __restrict__ z0,
                                                   const float* __restrict__ z1,
                                                   short* __restrict__ p) {
    int t = threadIdx.x;
    int c = blockIdx.x;  // 8192 blocks, 8192 floats (128 pairs) each
    const float* src = (c < 4096) ? z0 + (long)c * 8192 : z1 + (long)(c - 4096) * 8192;
    int g = t >> 2, sub = t & 3;           // 64 groups x 4 lanes; group g owns pairs 2g,2g+1
    const float* base = src + g * 128 + sub * 4;
    float4 v[8];
#pragma unroll
    for (int j = 0; j < 8; ++j) v[j] = *(const float4*)(base + j * 16);
    float sA = 0.f, sB = 0.f;
#pragma unroll
    for (int j = 0; j < 4; ++j) sA += v[j].x + v[j].y + v[j].z + v[j].w;
#pragma unroll
    for (int j = 4; j < 8; ++j) sB += v[j].x + v[j].y + v[j].z + v[j].w;
    sA = qsum(sA);
    sB = qsum(sB);
    if (sub == 0) {
        int pk = (int)(unsigned short)f2bf(sA * (1.0f / 64.0f))
               | ((int)(unsigned short)f2bf(sB * (1.0f / 64.0f)) << 16);
        ((int*)p)[c * 64 + g] = pk;
    }
}

// XOR-swizzled LDS address (shorts). stride 256, 16B-granule swizzle.
__device__ __forceinline__ int swz(int r, int k) { return r * 256 + (k ^ ((r & 7) << 3)); }

// ---- 2. bf16 NT GEMM: 64x64 tile, BK=256, 4 waves split K, LDS reduce ----
// C[z] [m][n] = sum_k A[m][k]*B[n][k] + bias[n].  B from bf16 (Bh) or fp32 (Bf,
// truncation-cast during staging).  Optional column sum/sumsq atomics (BN).
__global__ __launch_bounds__(256) void gemm_ks(const short* __restrict__ A,
                                               const short* __restrict__ Bh,
                                               const float* __restrict__ Bf,
                                               const float* __restrict__ bias,
                                               float* __restrict__ C,
                                               float* __restrict__ stats,
                                               int M, int N, int K, int kChunk) {
    __shared__ short sm[2 * 64 * 256];   // 64 KB; aliased as fp32 for reduce
    short* lA = sm;
    short* lB = sm + 64 * 256;
    int t = threadIdx.x;
    int n0 = blockIdx.x * 64, m0 = blockIdx.y * 64;
    int kbase = blockIdx.z * kChunk;
    long zoff = (long)blockIdx.z * M * N;
    int lane = t & 63, w = t >> 6;
    int l16 = lane & 15, quad = lane >> 4;
    int ks = w * 64;                     // this wave's K-slice inside BK
    f4v acc[4][4] = {};
    int sr = t >> 3;                     // 0..31 staging row
    int sq8 = (t & 7) * 8;               // 0..56 staging k-offset

    for (int it = 0; it < kChunk; it += 256) {
        int k0 = kbase + it;
#pragma unroll
        for (int pp = 0; pp < 2; ++pp) {
            int r = sr + pp * 32;
            const short* as = &A[(long)(m0 + r) * K + k0];
#pragma unroll
            for (int j = 0; j < 4; ++j)
                *(s8v*)&lA[swz(r, sq8 + j * 64)] = *(const s8v*)&as[sq8 + j * 64];
        }
        if (Bh) {
#pragma unroll
            for (int pp = 0; pp < 2; ++pp) {
                int r = sr + pp * 32;
                const short* bs = &Bh[(long)(n0 + r) * K + k0];
#pragma unroll
                for (int j = 0; j < 4; ++j)
                    *(s8v*)&lB[swz(r, sq8 + j * 64)] = *(const s8v*)&bs[sq8 + j * 64];
            }
        } else {
#pragma unroll
            for (int pp = 0; pp < 2; ++pp) {
                int r = sr + pp * 32;
                const float* bs = &Bf[(long)(n0 + r) * K + k0];
#pragma unroll
                for (int j = 0; j < 4; ++j) {
                    float4 x = *(const float4*)&bs[sq8 + j * 64];
                    float4 y = *(const float4*)&bs[sq8 + j * 64 + 4];
                    int4 o;
                    o.x = pk_trunc(x.x, x.y);
                    o.y = pk_trunc(x.z, x.w);
                    o.z = pk_trunc(y.x, y.y);
                    o.w = pk_trunc(y.z, y.w);
                    *(int4*)&lB[swz(r, sq8 + j * 64)] = o;
                }
            }
        }
        __syncthreads();
#pragma unroll
        for (int kk = 0; kk < 2; ++kk) {
            s8v af[4], bf[4];
#pragma unroll
            for (int i = 0; i < 4; ++i)
                af[i] = *(const s8v*)&lA[swz(i * 16 + l16, ks + kk * 32 + quad * 8)];
#pragma unroll
            for (int j = 0; j < 4; ++j)
                bf[j] = *(const s8v*)&lB[swz(j * 16 + l16, ks + kk * 32 + quad * 8)];
#pragma unroll
            for (int i = 0; i < 4; ++i)
#pragma unroll
                for (int j = 0; j < 4; ++j)
                    acc[i][j] = __builtin_amdgcn_mfma_f32_16x16x32_bf16(af[i], bf[j], acc[i][j], 0, 0, 0);
        }
        __syncthreads();
    }

    // cross-wave K reduction: each wave dumps 64x64 fp32 partial, then
    // thread t finalizes col c = t&63, rows (t>>6)*16 .. +16.
    float* fr = (float*)sm;
#pragma unroll
    for (int i = 0; i < 4; ++i)
#pragma unroll
        for (int j = 0; j < 4; ++j)
#pragma unroll
            for (int r = 0; r < 4; ++r)
                fr[w * 4096 + (i * 16 + quad * 4 + r) * 64 + j * 16 + l16] = acc[i][j][r];
    __syncthreads();
    int c = t & 63;
    int rbase = (t >> 6) * 16;
    float bv = bias ? bias[n0 + c] : 0.0f;
    float s = 0.f, q = 0.f;
#pragma unroll
    for (int r = 0; r < 16; ++r) {
        int rr = rbase + r;
        float h = fr[rr * 64 + c] + fr[4096 + rr * 64 + c]
                + fr[8192 + rr * 64 + c] + fr[12288 + rr * 64 + c] + bv;
        C[zoff + (long)(m0 + rr) * N + n0 + c] = h;
        s += h; q += h * h;
    }
    if (stats) {
        __syncthreads();
        fr[(t >> 6) * 64 + c] = s;
        fr[256 + (t >> 6) * 64 + c] = q;
        __syncthreads();
        if (t < 64) {
            float ss = fr[t] + fr[64 + t] + fr[128 + t] + fr[192 + t];
            float qq = fr[256 + t] + fr[320 + t] + fr[384 + t] + fr[448 + t];
            atomicAdd(&stats[n0 + t], ss);
            atomicAdd(&stats[2048 + n0 + t], qq);
        }
    }
}

// ---- 3. BN finalize: stats -> scale/shift ----
__global__ __launch_bounds__(256) void bn_finalize(const float* __restrict__ stats,
                                                   const float* __restrict__ gamma,
                                                   const float* __restrict__ beta,
                                                   float* __restrict__ scale,
                                                   float* __restrict__ shift) {
    int c = blockIdx.x * 256 + threadIdx.x;
    float mu = stats[c] * (1.0f / NROW);
    float var = stats[2048 + c] * (1.0f / NROW) - mu * mu;
    float sc = gamma[c] * rsqrtf(var + 1e-5f);
    scale[c] = sc;
    shift[c] = beta[c] - mu * sc;
}

// ---- 4. bn apply + relu + cast bf16 ----
__global__ __launch_bounds__(256) void bn_relu_cast(const float* __restrict__ h,
                                                    const float* __restrict__ scale,
                                                    const float* __restrict__ shift,
                                                    short* __restrict__ hn) {
    int idx = (blockIdx.x * 256 + threadIdx.x) * 4;
    int col = idx & (DIM - 1);
    float4 v = *(const float4*)(h + idx);
    float4 sc = *(const float4*)(scale + col);
    float4 sh = *(const float4*)(shift + col);
    s4v o;
    o.x = f2bf(fmaxf(v.x * sc.x + sh.x, 0.f));
    o.y = f2bf(fmaxf(v.y * sc.y + sh.y, 0.f));
    o.z = f2bf(fmaxf(v.z * sc.z + sh.z, 0.f));
    o.w = f2bf(fmaxf(v.w * sc.w + sh.w, 0.f));
    *(s4v*)(hn + idx) = o;
}

// ---- 5. row L2 normalize + cast bf16 ----
__global__ __launch_bounds__(256) void rownorm(const float* __restrict__ z,
                                               short* __restrict__ zn) {
    __shared__ float red[4];
    int row = blockIdx.x, t = threadIdx.x;
    const float* zr = z + (long)row * DIM;
    float4 v0 = *(const float4*)(zr + t * 4);
    float4 v1 = *(const float4*)(zr + 1024 + t * 4);
    float ss = v0.x * v0.x + v0.y * v0.y + v0.z * v0.z + v0.w * v0.w
             + v1.x * v1.x + v1.y * v1.y + v1.z * v1.z + v1.w * v1.w;
#pragma unroll
    for (int m = 1; m < 64; m <<= 1) ss += __shfl_xor(ss, m);
    if ((t & 63) == 0) red[t >> 6] = ss;
    __syncthreads();
    float tot = red[0] + red[1] + red[2] + red[3];
    float inv = 1.0f / fmaxf(sqrtf(tot), 1e-8f);
    s4v a, b;
    a.x = f2bf(v0.x * inv); a.y = f2bf(v0.y * inv); a.z = f2bf(v0.z * inv); a.w = f2bf(v0.w * inv);
    b.x = f2bf(v1.x * inv); b.y = f2bf(v1.y * inv); b.z = f2bf(v1.z * inv); b.w = f2bf(v1.w * inv);
    *(s4v*)(zn + (long)row * DIM + t * 4) = a;
    *(s4v*)(zn + (long)row * DIM + 1024 + t * 4) = b;
}

// ---- 6. sum 8 split-K partials -> sim; zero the 2-float output ----
__global__ __launch_bounds__(256) void ksum8(const float* __restrict__ simp,
                                             float* __restrict__ sim,
                                             float* __restrict__ out) {
    int idx = (blockIdx.x * 256 + threadIdx.x) * 4;
    float4 o = {0.f, 0.f, 0.f, 0.f};
#pragma unroll
    for (int z = 0; z < 8; ++z) {
        float4 a = *(const float4*)(simp + (long)z * 131072 + idx);
        o.x += a.x; o.y += a.y; o.z += a.z; o.w += a.w;
    }
    *(float4*)(sim + idx) = o;
    if (blockIdx.x == 0 && threadIdx.x == 0) { out[0] = 0.f; out[1] = 0.f; }
}

// ---- 7. loss: one row per wave, 64 blocks x 4 waves, atomicAdd finish ----
__global__ __launch_bounds__(256) void loss_kernel(const float* __restrict__ sim,
                                                   const int* __restrict__ rel,
                                                   float* __restrict__ out) {
    __shared__ float lsum[4];
    __shared__ float lcnt[4];
    int t = threadIdx.x, lane = t & 63, wave = t >> 6;
    int i = blockIdx.x * 4 + wave;
    int reli = rel[i];
    float s[8];
    float neg = 0.f;
#pragma unroll
    for (int kk = 0; kk < 8; ++kk) {
        int j = lane + kk * 64;
        s[kk] = sim[i * 512 + j];
        float e = __expf(10.0f * s[kk]);
        if (j >= NB || abs(reli - rel[j]) > 2) neg += e;
    }
#pragma unroll
    for (int m = 1; m < 64; m <<= 1) neg += __shfl_xor(neg, m);
    float ts = 0.f; int cnt = 0;
#pragma unroll
    for (int kk = 0; kk < 4; ++kk) {
        int j = lane + kk * 64;
        if (j != i && abs(reli - rel[j]) <= 2) {
            ts += logf(__expf(10.0f * s[kk]) + neg) - 10.0f * s[kk];
            cnt++;
        }
    }
#pragma unroll
    for (int m = 1; m < 64; m <<= 1) {
        ts += __shfl_xor(ts, m);
        cnt += __shfl_xor(cnt, m);
    }
    if (lane == 0) {
        lsum[wave] = (cnt > 0) ? ts / (float)cnt : 0.f;
        lcnt[wave] = (cnt > 0) ? 1.f : 0.f;
    }
    __syncthreads();
    if (t == 0) {
        atomicAdd(&out[0], lsum[0] + lsum[1] + lsum[2] + lsum[3]);
        atomicAdd(&out[1], lcnt[0] + lcnt[1] + lcnt[2] + lcnt[3]);
    }
}

extern "C" void kernel_launch(void* const* d_in, const int* in_sizes, int n_in,
                              void* d_out, int out_size, void* d_ws, size_t ws_size,
                              hipStream_t stream) {
    const float* z0    = (const float*)d_in[0];
    const float* z1    = (const float*)d_in[1];
    const int*   rel0  = (const int*)d_in[2];
    const float* W1    = (const float*)d_in[4];
    const float* b1    = (const float*)d_in[5];
    const float* gamma = (const float*)d_in[6];
    const float* beta  = (const float*)d_in[7];
    const float* W2    = (const float*)d_in[8];
    const float* b2    = (const float*)d_in[9];

    char* ws = (char*)d_ws;
    short* p_bf  = (short*)(ws);                         // 2 MB
    float* h     = (float*)(ws + (2l  << 20));           // 4 MB
    short* hn    = (short*)(ws + (6l  << 20));           // 2 MB
    float* zproj = (float*)(ws + (8l  << 20));           // 4 MB
    short* zn    = (short*)(ws + (12l << 20));           // 2 MB
    float* simp  = (float*)(ws + (14l << 20));           // 4 MB (8 x 512 KB)
    float* sim   = (float*)(ws + (18l << 20));           // 512 KB
    float* stats = (float*)(ws + (19l << 20));           // 16 KB (sum | sumsq)
    float* scale = (float*)(ws + (19l << 20) + 16384);   // 8 KB
    float* shift = (float*)(ws + (19l << 20) + 24576);   // 8 KB

    hipMemsetAsync(stats, 0, 16384, stream);
    pool_kernel<<<8192, 256, 0, stream>>>(z0, z1, p_bf);
    gemm_ks<<<dim3(32, 8, 1), 256, 0, stream>>>(p_bf, nullptr, W1, b1, h, stats,
                                                NROW, DIM, DIM, DIM);
    bn_finalize<<<8, 256, 0, stream>>>(stats, gamma, beta, scale, shift);
    bn_relu_cast<<<1024, 256, 0, stream>>>(h, scale, shift, hn);
    gemm_ks<<<dim3(32, 8, 1), 256, 0, stream>>>(hn, nullptr, W2, b2, zproj, nullptr,
                                                NROW, DIM, DIM, DIM);
    rownorm<<<512, 256, 0, stream>>>(zproj, zn);
    gemm_ks<<<dim3(8, 4, 8), 256, 0, stream>>>(zn, zn, nullptr, nullptr, simp, nullptr,
                                               NB, NROW, DIM, 256);
    ksum8<<<128, 256, 0, stream>>>(simp, sim, (float*)d_out);
    loss_kernel<<<64, 256, 0, stream>>>(sim, rel0, (float*)d_out);
}

// Round 2
// 340.496 us; speedup vs baseline: 1.0951x; 1.0767x over previous
//
#include <hip/hip_runtime.h>

typedef __attribute__((ext_vector_type(8))) short s8v;
typedef __attribute__((ext_vector_type(4))) short s4v;
typedef __attribute__((ext_vector_type(4))) float f4v;

#define DIM 2048
#define NROW 512   // 2*B
#define NB 256     // B

__device__ inline short f2bf(float f) {
    union { float f; unsigned int u; } v; v.f = f;
    unsigned int u = v.u;
    unsigned int r = (u + 0x7fffu + ((u >> 16) & 1u)) >> 16;
    return (short)r;
}

// pack two floats -> two truncated bf16 in one int (v_perm_b32).
// D.bytes = [a.b2, a.b3, b.b2, b.b3]  => low short = bf16(a), high short = bf16(b)
__device__ __forceinline__ int pk_trunc(float a, float b) {
    return __builtin_amdgcn_perm(__float_as_uint(b), __float_as_uint(a), 0x07060302);
}

// sum across a quad of lanes via DPP quad_perm (VALU only, no LDS pipe)
__device__ __forceinline__ float qsum(float s) {
    int i = __float_as_int(s);
    s += __int_as_float(__builtin_amdgcn_update_dpp(i, i, 0xB1, 0xF, 0xF, false)); // [1,0,3,2]
    i = __float_as_int(s);
    s += __int_as_float(__builtin_amdgcn_update_dpp(i, i, 0x4E, 0xF, 0xF, false)); // [2,3,0,1]
    return s;
}

// ---- 1. spatial mean pool, non-temporal stream ----
// z0+z1 = 268.4 MB ~= L3 capacity: cached reads thrash the L3 at ~2.8 TB/s
// combined (50% hit steady state, every byte through the fill/evict path).
// nt loads mark the stream no-allocate/evict-first -> straight HBM stream.
__global__ __launch_bounds__(256) void pool_kernel(const float* __restrict__ z0,
                                                   const float* __restrict__ z1,
                                                   short* __restrict__ p) {
    int t = threadIdx.x;
    int c = blockIdx.x;  // 8192 blocks, 8192 floats (128 pairs) each
    const float* src = (c < 4096) ? z0 + (long)c * 8192 : z1 + (long)(c - 4096) * 8192;
    int g = t >> 2, sub = t & 3;           // 64 groups x 4 lanes; group g owns pairs 2g,2g+1
    const float* base = src + g * 128 + sub * 4;
    f4v v[8];
#pragma unroll
    for (int j = 0; j < 8; ++j) v[j] = __builtin_nontemporal_load((const f4v*)(base + j * 16));
    float sA = 0.f, sB = 0.f;
#pragma unroll
    for (int j = 0; j < 4; ++j) sA += v[j].x + v[j].y + v[j].z + v[j].w;
#pragma unroll
    for (int j = 4; j < 8; ++j) sB += v[j].x + v[j].y + v[j].z + v[j].w;
    sA = qsum(sA);
    sB = qsum(sB);
    if (sub == 0) {
        int pk = (int)(unsigned short)f2bf(sA * (1.0f / 64.0f))
               | ((int)(unsigned short)f2bf(sB * (1.0f / 64.0f)) << 16);
        ((int*)p)[c * 64 + g] = pk;
    }
}

// ---- 1b. W fp32 -> bf16 pre-cast (truncation, identical numerics to the
// in-staging pk_trunc path). Read once (nt), written cached for gemm reuse.
__global__ __launch_bounds__(256) void castw(const float* __restrict__ w,
                                             short* __restrict__ o) {
    int idx = (blockIdx.x * 256 + threadIdx.x) * 8;
    f4v x = __builtin_nontemporal_load((const f4v*)(w + idx));
    f4v y = __builtin_nontemporal_load((const f4v*)(w + idx + 4));
    int4 o4;
    o4.x = pk_trunc(x.x, x.y);
    o4.y = pk_trunc(x.z, x.w);
    o4.z = pk_trunc(y.x, y.y);
    o4.w = pk_trunc(y.z, y.w);
    *(int4*)(o + idx) = o4;
}

// XOR-swizzled LDS address (shorts). stride 256, 16B-granule swizzle.
__device__ __forceinline__ int swz(int r, int k) { return r * 256 + (k ^ ((r & 7) << 3)); }

// ---- 2. bf16 NT GEMM: 64x64 tile, BK=256, 4 waves split K, LDS reduce ----
// C[z] [m][n] = sum_k A[m][k]*B[n][k] + bias[n].  B from bf16 (Bh) or fp32 (Bf,
// truncation-cast during staging).  Optional column sum/sumsq atomics (BN).
__global__ __launch_bounds__(256) void gemm_ks(const short* __restrict__ A,
                                               const short* __restrict__ Bh,
                                               const float* __restrict__ Bf,
                                               const float* __restrict__ bias,
                                               float* __restrict__ C,
                                               float* __restrict__ stats,
                                               int M, int N, int K, int kChunk) {
    __shared__ short sm[2 * 64 * 256];   // 64 KB; aliased as fp32 for reduce
    short* lA = sm;
    short* lB = sm + 64 * 256;
    int t = threadIdx.x;
    int n0 = blockIdx.x * 64, m0 = blockIdx.y * 64;
    int kbase = blockIdx.z * kChunk;
    long zoff = (long)blockIdx.z * M * N;
    int lane = t & 63, w = t >> 6;
    int l16 = lane & 15, quad = lane >> 4;
    int ks = w * 64;                     // this wave's K-slice inside BK
    f4v acc[4][4] = {};
    int sr = t >> 3;                     // 0..31 staging row
    int sq8 = (t & 7) * 8;               // 0..56 staging k-offset

    for (int it = 0; it < kChunk; it += 256) {
        int k0 = kbase + it;
#pragma unroll
        for (int pp = 0; pp < 2; ++pp) {
            int r = sr + pp * 32;
            const short* as = &A[(long)(m0 + r) * K + k0];
#pragma unroll
            for (int j = 0; j < 4; ++j)
                *(s8v*)&lA[swz(r, sq8 + j * 64)] = *(const s8v*)&as[sq8 + j * 64];
        }
        if (Bh) {
#pragma unroll
            for (int pp = 0; pp < 2; ++pp) {
                int r = sr + pp * 32;
                const short* bs = &Bh[(long)(n0 + r) * K + k0];
#pragma unroll
                for (int j = 0; j < 4; ++j)
                    *(s8v*)&lB[swz(r, sq8 + j * 64)] = *(const s8v*)&bs[sq8 + j * 64];
            }
        } else {
#pragma unroll
            for (int pp = 0; pp < 2; ++pp) {
                int r = sr + pp * 32;
                const float* bs = &Bf[(long)(n0 + r) * K + k0];
#pragma unroll
                for (int j = 0; j < 4; ++j) {
                    float4 x = *(const float4*)&bs[sq8 + j * 64];
                    float4 y = *(const float4*)&bs[sq8 + j * 64 + 4];
                    int4 o;
                    o.x = pk_trunc(x.x, x.y);
                    o.y = pk_trunc(x.z, x.w);
                    o.z = pk_trunc(y.x, y.y);
                    o.w = pk_trunc(y.z, y.w);
                    *(int4*)&lB[swz(r, sq8 + j * 64)] = o;
                }
            }
        }
        __syncthreads();
#pragma unroll
        for (int kk = 0; kk < 2; ++kk) {
            s8v af[4], bf[4];
#pragma unroll
            for (int i = 0; i < 4; ++i)
                af[i] = *(const s8v*)&lA[swz(i * 16 + l16, ks + kk * 32 + quad * 8)];
#pragma unroll
            for (int j = 0; j < 4; ++j)
                bf[j] = *(const s8v*)&lB[swz(j * 16 + l16, ks + kk * 32 + quad * 8)];
#pragma unroll
            for (int i = 0; i < 4; ++i)
#pragma unroll
                for (int j = 0; j < 4; ++j)
                    acc[i][j] = __builtin_amdgcn_mfma_f32_16x16x32_bf16(af[i], bf[j], acc[i][j], 0, 0, 0);
        }
        __syncthreads();
    }

    // cross-wave K reduction: each wave dumps 64x64 fp32 partial, then
    // thread t finalizes col c = t&63, rows (t>>6)*16 .. +16.
    float* fr = (float*)sm;
#pragma unroll
    for (int i = 0; i < 4; ++i)
#pragma unroll
        for (int j = 0; j < 4; ++j)
#pragma unroll
            for (int r = 0; r < 4; ++r)
                fr[w * 4096 + (i * 16 + quad * 4 + r) * 64 + j * 16 + l16] = acc[i][j][r];
    __syncthreads();
    int c = t & 63;
    int rbase = (t >> 6) * 16;
    float bv = bias ? bias[n0 + c] : 0.0f;
    float s = 0.f, q = 0.f;
#pragma unroll
    for (int r = 0; r < 16; ++r) {
        int rr = rbase + r;
        float h = fr[rr * 64 + c] + fr[4096 + rr * 64 + c]
                + fr[8192 + rr * 64 + c] + fr[12288 + rr * 64 + c] + bv;
        C[zoff + (long)(m0 + rr) * N + n0 + c] = h;
        s += h; q += h * h;
    }
    if (stats) {
        __syncthreads();
        fr[(t >> 6) * 64 + c] = s;
        fr[256 + (t >> 6) * 64 + c] = q;
        __syncthreads();
        if (t < 64) {
            float ss = fr[t] + fr[64 + t] + fr[128 + t] + fr[192 + t];
            float qq = fr[256 + t] + fr[320 + t] + fr[384 + t] + fr[448 + t];
            atomicAdd(&stats[n0 + t], ss);
            atomicAdd(&stats[2048 + n0 + t], qq);
        }
    }
}

// ---- 3. BN finalize: stats -> scale/shift ----
__global__ __launch_bounds__(256) void bn_finalize(const float* __restrict__ stats,
                                                   const float* __restrict__ gamma,
                                                   const float* __restrict__ beta,
                                                   float* __restrict__ scale,
                                                   float* __restrict__ shift) {
    int c = blockIdx.x * 256 + threadIdx.x;
    float mu = stats[c] * (1.0f / NROW);
    float var = stats[2048 + c] * (1.0f / NROW) - mu * mu;
    float sc = gamma[c] * rsqrtf(var + 1e-5f);
    scale[c] = sc;
    shift[c] = beta[c] - mu * sc;
}

// ---- 4. bn apply + relu + cast bf16 ----
__global__ __launch_bounds__(256) void bn_relu_cast(const float* __restrict__ h,
                                                    const float* __restrict__ scale,
                                                    const float* __restrict__ shift,
                                                    short* __restrict__ hn) {
    int idx = (blockIdx.x * 256 + threadIdx.x) * 4;
    int col = idx & (DIM - 1);
    float4 v = *(const float4*)(h + idx);
    float4 sc = *(const float4*)(scale + col);
    float4 sh = *(const float4*)(shift + col);
    s4v o;
    o.x = f2bf(fmaxf(v.x * sc.x + sh.x, 0.f));
    o.y = f2bf(fmaxf(v.y * sc.y + sh.y, 0.f));
    o.z = f2bf(fmaxf(v.z * sc.z + sh.z, 0.f));
    o.w = f2bf(fmaxf(v.w * sc.w + sh.w, 0.f));
    *(s4v*)(hn + idx) = o;
}

// ---- 5. row L2 normalize + cast bf16 ----
__global__ __launch_bounds__(256) void rownorm(const float* __restrict__ z,
                                               short* __restrict__ zn) {
    __shared__ float red[4];
    int row = blockIdx.x, t = threadIdx.x;
    const float* zr = z + (long)row * DIM;
    float4 v0 = *(const float4*)(zr + t * 4);
    float4 v1 = *(const float4*)(zr + 1024 + t * 4);
    float ss = v0.x * v0.x + v0.y * v0.y + v0.z * v0.z + v0.w * v0.w
             + v1.x * v1.x + v1.y * v1.y + v1.z * v1.z + v1.w * v1.w;
#pragma unroll
    for (int m = 1; m < 64; m <<= 1) ss += __shfl_xor(ss, m);
    if ((t & 63) == 0) red[t >> 6] = ss;
    __syncthreads();
    float tot = red[0] + red[1] + red[2] + red[3];
    float inv = 1.0f / fmaxf(sqrtf(tot), 1e-8f);
    s4v a, b;
    a.x = f2bf(v0.x * inv); a.y = f2bf(v0.y * inv); a.z = f2bf(v0.z * inv); a.w = f2bf(v0.w * inv);
    b.x = f2bf(v1.x * inv); b.y = f2bf(v1.y * inv); b.z = f2bf(v1.z * inv); b.w = f2bf(v1.w * inv);
    *(s4v*)(zn + (long)row * DIM + t * 4) = a;
    *(s4v*)(zn + (long)row * DIM + 1024 + t * 4) = b;
}

// ---- 6. sum 8 split-K partials -> sim; zero the 2-float output ----
__global__ __launch_bounds__(256) void ksum8(const float* __restrict__ simp,
                                             float* __restrict__ sim,
                                             float* __restrict__ out) {
    int idx = (blockIdx.x * 256 + threadIdx.x) * 4;
    float4 o = {0.f, 0.f, 0.f, 0.f};
#pragma unroll
    for (int z = 0; z < 8; ++z) {
        float4 a = *(const float4*)(simp + (long)z * 131072 + idx);
        o.x += a.x; o.y += a.y; o.z += a.z; o.w += a.w;
    }
    *(float4*)(sim + idx) = o;
    if (blockIdx.x == 0 && threadIdx.x == 0) { out[0] = 0.f; out[1] = 0.f; }
}

// ---- 7. loss: one row per wave, 64 blocks x 4 waves, atomicAdd finish ----
__global__ __launch_bounds__(256) void loss_kernel(const float* __restrict__ sim,
                                                   const int* __restrict__ rel,
                                                   float* __restrict__ out) {
    __shared__ float lsum[4];
    __shared__ float lcnt[4];
    int t = threadIdx.x, lane = t & 63, wave = t >> 6;
    int i = blockIdx.x * 4 + wave;
    int reli = rel[i];
    float s[8];
    float neg = 0.f;
#pragma unroll
    for (int kk = 0; kk < 8; ++kk) {
        int j = lane + kk * 64;
        s[kk] = sim[i * 512 + j];
        float e = __expf(10.0f * s[kk]);
        if (j >= NB || abs(reli - rel[j]) > 2) neg += e;
    }
#pragma unroll
    for (int m = 1; m < 64; m <<= 1) neg += __shfl_xor(neg, m);
    float ts = 0.f; int cnt = 0;
#pragma unroll
    for (int kk = 0; kk < 4; ++kk) {
        int j = lane + kk * 64;
        if (j != i && abs(reli - rel[j]) <= 2) {
            ts += logf(__expf(10.0f * s[kk]) + neg) - 10.0f * s[kk];
            cnt++;
        }
    }
#pragma unroll
    for (int m = 1; m < 64; m <<= 1) {
        ts += __shfl_xor(ts, m);
        cnt += __shfl_xor(cnt, m);
    }
    if (lane == 0) {
        lsum[wave] = (cnt > 0) ? ts / (float)cnt : 0.f;
        lcnt[wave] = (cnt > 0) ? 1.f : 0.f;
    }
    __syncthreads();
    if (t == 0) {
        atomicAdd(&out[0], lsum[0] + lsum[1] + lsum[2] + lsum[3]);
        atomicAdd(&out[1], lcnt[0] + lcnt[1] + lcnt[2] + lcnt[3]);
    }
}

extern "C" void kernel_launch(void* const* d_in, const int* in_sizes, int n_in,
                              void* d_out, int out_size, void* d_ws, size_t ws_size,
                              hipStream_t stream) {
    const float* z0    = (const float*)d_in[0];
    const float* z1    = (const float*)d_in[1];
    const int*   rel0  = (const int*)d_in[2];
    const float* W1    = (const float*)d_in[4];
    const float* b1    = (const float*)d_in[5];
    const float* gamma = (const float*)d_in[6];
    const float* beta  = (const float*)d_in[7];
    const float* W2    = (const float*)d_in[8];
    const float* b2    = (const float*)d_in[9];

    char* ws = (char*)d_ws;
    short* p_bf  = (short*)(ws);                         // 2 MB
    float* h     = (float*)(ws + (2l  << 20));           // 4 MB
    short* hn    = (short*)(ws + (6l  << 20));           // 2 MB
    float* zproj = (float*)(ws + (8l  << 20));           // 4 MB
    short* zn    = (short*)(ws + (12l << 20));           // 2 MB
    float* simp  = (float*)(ws + (14l << 20));           // 4 MB (8 x 512 KB)
    float* sim   = (float*)(ws + (18l << 20));           // 512 KB
    float* stats = (float*)(ws + (19l << 20));           // 16 KB (sum | sumsq)
    float* scale = (float*)(ws + (19l << 20) + 16384);   // 8 KB
    float* shift = (float*)(ws + (19l << 20) + 24576);   // 8 KB
    short* w1h   = (short*)(ws + (20l << 20));           // 8 MB bf16 W1
    short* w2h   = (short*)(ws + (28l << 20));           // 8 MB bf16 W2
    bool castok = ws_size >= (36l << 20);

    hipMemsetAsync(stats, 0, 16384, stream);
    if (castok) {
        castw<<<2048, 256, 0, stream>>>(W1, w1h);
        castw<<<2048, 256, 0, stream>>>(W2, w2h);
    }
    pool_kernel<<<8192, 256, 0, stream>>>(z0, z1, p_bf);
    gemm_ks<<<dim3(32, 8, 1), 256, 0, stream>>>(p_bf, castok ? w1h : nullptr,
                                                castok ? nullptr : W1, b1, h, stats,
                                                NROW, DIM, DIM, DIM);
    bn_finalize<<<8, 256, 0, stream>>>(stats, gamma, beta, scale, shift);
    bn_relu_cast<<<1024, 256, 0, stream>>>(h, scale, shift, hn);
    gemm_ks<<<dim3(32, 8, 1), 256, 0, stream>>>(hn, castok ? w2h : nullptr,
                                                castok ? nullptr : W2, b2, zproj, nullptr,
                                                NROW, DIM, DIM, DIM);
    rownorm<<<512, 256, 0, stream>>>(zproj, zn);
    gemm_ks<<<dim3(8, 4, 8), 256, 0, stream>>>(zn, zn, nullptr, nullptr, simp, nullptr,
                                               NB, NROW, DIM, 256);
    ksum8<<<128, 256, 0, stream>>>(simp, sim, (float*)d_out);
    loss_kernel<<<64, 256, 0, stream>>>(sim, rel0, (float*)d_out);
}

// Round 3
// 337.057 us; speedup vs baseline: 1.1062x; 1.0102x over previous
//
#include <hip/hip_runtime.h>

typedef __attribute__((ext_vector_type(8))) short s8v;
typedef __attribute__((ext_vector_type(4))) short s4v;
typedef __attribute__((ext_vector_type(4))) float f4v;

#define DIM 2048
#define NROW 512   // 2*B
#define NB 256     // B

__device__ inline short f2bf(float f) {
    union { float f; unsigned int u; } v; v.f = f;
    unsigned int u = v.u;
    unsigned int r = (u + 0x7fffu + ((u >> 16) & 1u)) >> 16;
    return (short)r;
}

// pack two floats -> two truncated bf16 in one int (v_perm_b32).
// D.bytes = [a.b2, a.b3, b.b2, b.b3]  => low short = bf16(a), high short = bf16(b)
__device__ __forceinline__ int pk_trunc(float a, float b) {
    return __builtin_amdgcn_perm(__float_as_uint(b), __float_as_uint(a), 0x07060302);
}

// sum across a quad of lanes via DPP quad_perm (VALU only, no LDS pipe)
__device__ __forceinline__ float qsum(float s) {
    int i = __float_as_int(s);
    s += __int_as_float(__builtin_amdgcn_update_dpp(i, i, 0xB1, 0xF, 0xF, false)); // [1,0,3,2]
    i = __float_as_int(s);
    s += __int_as_float(__builtin_amdgcn_update_dpp(i, i, 0x4E, 0xF, 0xF, false)); // [2,3,0,1]
    return s;
}

// ---- 1. fused: spatial mean pool (nt stream) + W1/W2 fp32->bf16 cast + stats zero ----
// Blocks 0..8191: pool 32 KB each (z0+z1 = 268 MB ~ L3 capacity -> nt loads
// bypass the thrashing L3, straight HBM stream). Blocks 8192..12287: cast one
// 8 KB W-slab each (nt read, cached write for gemm reuse). First cast block
// also zeroes the 16 KB stats buffer (replaces hipMemsetAsync dispatch).
__global__ __launch_bounds__(256) void pool_cast(const float* __restrict__ z0,
                                                 const float* __restrict__ z1,
                                                 const float* __restrict__ W1,
                                                 const float* __restrict__ W2,
                                                 short* __restrict__ p,
                                                 short* __restrict__ w1h,
                                                 short* __restrict__ w2h,
                                                 float* __restrict__ stats) {
    int t = threadIdx.x;
    int c = blockIdx.x;
    if (c < 8192) {
        const float* src = (c < 4096) ? z0 + (long)c * 8192 : z1 + (long)(c - 4096) * 8192;
        int g = t >> 2, sub = t & 3;       // 64 groups x 4 lanes; group g owns pairs 2g,2g+1
        const float* base = src + g * 128 + sub * 4;
        f4v v[8];
#pragma unroll
        for (int j = 0; j < 8; ++j) v[j] = __builtin_nontemporal_load((const f4v*)(base + j * 16));
        __builtin_amdgcn_sched_barrier(0);  // keep all 8 loads issued before the reduce
        float sA = 0.f, sB = 0.f;
#pragma unroll
        for (int j = 0; j < 4; ++j) sA += v[j].x + v[j].y + v[j].z + v[j].w;
#pragma unroll
        for (int j = 4; j < 8; ++j) sB += v[j].x + v[j].y + v[j].z + v[j].w;
        sA = qsum(sA);
        sB = qsum(sB);
        if (sub == 0) {
            int pk = (int)(unsigned short)f2bf(sA * (1.0f / 64.0f))
                   | ((int)(unsigned short)f2bf(sB * (1.0f / 64.0f)) << 16);
            ((int*)p)[c * 64 + g] = pk;
        }
    } else {
        int cc = c - 8192;                  // 0..4095: 2048 slabs per W
        const float* w = (cc < 2048) ? W1 : W2;
        short* o = (cc < 2048) ? w1h : w2h;
        int idx = (cc & 2047) * 2048 + t * 8;
        f4v x = __builtin_nontemporal_load((const f4v*)(w + idx));
        f4v y = __builtin_nontemporal_load((const f4v*)(w + idx + 4));
        int4 o4;
        o4.x = pk_trunc(x.x, x.y);
        o4.y = pk_trunc(x.z, x.w);
        o4.z = pk_trunc(y.x, y.y);
        o4.w = pk_trunc(y.z, y.w);
        *(int4*)(o + idx) = o4;
        if (cc == 0) {                      // zero 4096-float stats buffer
#pragma unroll
            for (int k = 0; k < 16; ++k) stats[t + k * 256] = 0.f;
        }
    }
}

// XOR-swizzled LDS address (shorts). stride 256, 16B-granule swizzle.
__device__ __forceinline__ int swz(int r, int k) { return r * 256 + (k ^ ((r & 7) << 3)); }

// ---- 2. bf16 NT GEMM: 64x64 tile, BK=256, 4 waves split K, LDS reduce ----
// C[z] [m][n] = sum_k A[m][k]*B[n][k] + bias[n].  B from bf16 (Bh) or fp32 (Bf,
// truncation-cast during staging).  Optional column sum/sumsq atomics (BN).
__global__ __launch_bounds__(256) void gemm_ks(const short* __restrict__ A,
                                               const short* __restrict__ Bh,
                                               const float* __restrict__ Bf,
                                               const float* __restrict__ bias,
                                               float* __restrict__ C,
                                               float* __restrict__ stats,
                                               int M, int N, int K, int kChunk) {
    __shared__ short sm[2 * 64 * 256];   // 64 KB; aliased as fp32 for reduce
    short* lA = sm;
    short* lB = sm + 64 * 256;
    int t = threadIdx.x;
    int n0 = blockIdx.x * 64, m0 = blockIdx.y * 64;
    int kbase = blockIdx.z * kChunk;
    long zoff = (long)blockIdx.z * M * N;
    int lane = t & 63, w = t >> 6;
    int l16 = lane & 15, quad = lane >> 4;
    int ks = w * 64;                     // this wave's K-slice inside BK
    f4v acc[4][4] = {};
    int sr = t >> 3;                     // 0..31 staging row
    int sq8 = (t & 7) * 8;               // 0..56 staging k-offset

    for (int it = 0; it < kChunk; it += 256) {
        int k0 = kbase + it;
#pragma unroll
        for (int pp = 0; pp < 2; ++pp) {
            int r = sr + pp * 32;
            const short* as = &A[(long)(m0 + r) * K + k0];
#pragma unroll
            for (int j = 0; j < 4; ++j)
                *(s8v*)&lA[swz(r, sq8 + j * 64)] = *(const s8v*)&as[sq8 + j * 64];
        }
        if (Bh) {
#pragma unroll
            for (int pp = 0; pp < 2; ++pp) {
                int r = sr + pp * 32;
                const short* bs = &Bh[(long)(n0 + r) * K + k0];
#pragma unroll
                for (int j = 0; j < 4; ++j)
                    *(s8v*)&lB[swz(r, sq8 + j * 64)] = *(const s8v*)&bs[sq8 + j * 64];
            }
        } else {
#pragma unroll
            for (int pp = 0; pp < 2; ++pp) {
                int r = sr + pp * 32;
                const float* bs = &Bf[(long)(n0 + r) * K + k0];
#pragma unroll
                for (int j = 0; j < 4; ++j) {
                    float4 x = *(const float4*)&bs[sq8 + j * 64];
                    float4 y = *(const float4*)&bs[sq8 + j * 64 + 4];
                    int4 o;
                    o.x = pk_trunc(x.x, x.y);
                    o.y = pk_trunc(x.z, x.w);
                    o.z = pk_trunc(y.x, y.y);
                    o.w = pk_trunc(y.z, y.w);
                    *(int4*)&lB[swz(r, sq8 + j * 64)] = o;
                }
            }
        }
        __syncthreads();
#pragma unroll
        for (int kk = 0; kk < 2; ++kk) {
            s8v af[4], bf[4];
#pragma unroll
            for (int i = 0; i < 4; ++i)
                af[i] = *(const s8v*)&lA[swz(i * 16 + l16, ks + kk * 32 + quad * 8)];
#pragma unroll
            for (int j = 0; j < 4; ++j)
                bf[j] = *(const s8v*)&lB[swz(j * 16 + l16, ks + kk * 32 + quad * 8)];
#pragma unroll
            for (int i = 0; i < 4; ++i)
#pragma unroll
                for (int j = 0; j < 4; ++j)
                    acc[i][j] = __builtin_amdgcn_mfma_f32_16x16x32_bf16(af[i], bf[j], acc[i][j], 0, 0, 0);
        }
        __syncthreads();
    }

    // cross-wave K reduction: each wave dumps 64x64 fp32 partial, then
    // thread t finalizes col c = t&63, rows (t>>6)*16 .. +16.
    float* fr = (float*)sm;
#pragma unroll
    for (int i = 0; i < 4; ++i)
#pragma unroll
        for (int j = 0; j < 4; ++j)
#pragma unroll
            for (int r = 0; r < 4; ++r)
                fr[w * 4096 + (i * 16 + quad * 4 + r) * 64 + j * 16 + l16] = acc[i][j][r];
    __syncthreads();
    int c = t & 63;
    int rbase = (t >> 6) * 16;
    float bv = bias ? bias[n0 + c] : 0.0f;
    float s = 0.f, q = 0.f;
#pragma unroll
    for (int r = 0; r < 16; ++r) {
        int rr = rbase + r;
        float h = fr[rr * 64 + c] + fr[4096 + rr * 64 + c]
                + fr[8192 + rr * 64 + c] + fr[12288 + rr * 64 + c] + bv;
        C[zoff + (long)(m0 + rr) * N + n0 + c] = h;
        s += h; q += h * h;
    }
    if (stats) {
        __syncthreads();
        fr[(t >> 6) * 64 + c] = s;
        fr[256 + (t >> 6) * 64 + c] = q;
        __syncthreads();
        if (t < 64) {
            float ss = fr[t] + fr[64 + t] + fr[128 + t] + fr[192 + t];
            float qq = fr[256 + t] + fr[320 + t] + fr[384 + t] + fr[448 + t];
            atomicAdd(&stats[n0 + t], ss);
            atomicAdd(&stats[2048 + n0 + t], qq);
        }
    }
}

// ---- 3. bn finalize+apply+relu+cast bf16 (scale/shift recomputed per thread
// from the 16 KB L2-resident stats; removes the bn_finalize dispatch) ----
__global__ __launch_bounds__(256) void bn_relu_cast(const float* __restrict__ h,
                                                    const float* __restrict__ stats,
                                                    const float* __restrict__ gamma,
                                                    const float* __restrict__ beta,
                                                    short* __restrict__ hn) {
    int idx = (blockIdx.x * 256 + threadIdx.x) * 4;
    int col = idx & (DIM - 1);
    float4 s0 = *(const float4*)(stats + col);
    float4 s1 = *(const float4*)(stats + 2048 + col);
    float4 g  = *(const float4*)(gamma + col);
    float4 bt = *(const float4*)(beta + col);
    float4 v  = *(const float4*)(h + idx);
    float mu, var, sc, sh;
    s4v o;
    mu = s0.x * (1.0f / NROW); var = s1.x * (1.0f / NROW) - mu * mu;
    sc = g.x * rsqrtf(var + 1e-5f); sh = bt.x - mu * sc;
    o.x = f2bf(fmaxf(v.x * sc + sh, 0.f));
    mu = s0.y * (1.0f / NROW); var = s1.y * (1.0f / NROW) - mu * mu;
    sc = g.y * rsqrtf(var + 1e-5f); sh = bt.y - mu * sc;
    o.y = f2bf(fmaxf(v.y * sc + sh, 0.f));
    mu = s0.z * (1.0f / NROW); var = s1.z * (1.0f / NROW) - mu * mu;
    sc = g.z * rsqrtf(var + 1e-5f); sh = bt.z - mu * sc;
    o.z = f2bf(fmaxf(v.z * sc + sh, 0.f));
    mu = s0.w * (1.0f / NROW); var = s1.w * (1.0f / NROW) - mu * mu;
    sc = g.w * rsqrtf(var + 1e-5f); sh = bt.w - mu * sc;
    o.w = f2bf(fmaxf(v.w * sc + sh, 0.f));
    *(s4v*)(hn + idx) = o;
}

// ---- 4. row L2 normalize + cast bf16; block 0 zeroes the loss accumulators ----
__global__ __launch_bounds__(256) void rownorm(const float* __restrict__ z,
                                               short* __restrict__ zn,
                                               float* __restrict__ out) {
    __shared__ float red[4];
    int row = blockIdx.x, t = threadIdx.x;
    if (row == 0 && t == 0) { out[0] = 0.f; out[1] = 0.f; }
    const float* zr = z + (long)row * DIM;
    float4 v0 = *(const float4*)(zr + t * 4);
    float4 v1 = *(const float4*)(zr + 1024 + t * 4);
    float ss = v0.x * v0.x + v0.y * v0.y + v0.z * v0.z + v0.w * v0.w
             + v1.x * v1.x + v1.y * v1.y + v1.z * v1.z + v1.w * v1.w;
#pragma unroll
    for (int m = 1; m < 64; m <<= 1) ss += __shfl_xor(ss, m);
    if ((t & 63) == 0) red[t >> 6] = ss;
    __syncthreads();
    float tot = red[0] + red[1] + red[2] + red[3];
    float inv = 1.0f / fmaxf(sqrtf(tot), 1e-8f);
    s4v a, b;
    a.x = f2bf(v0.x * inv); a.y = f2bf(v0.y * inv); a.z = f2bf(v0.z * inv); a.w = f2bf(v0.w * inv);
    b.x = f2bf(v1.x * inv); b.y = f2bf(v1.y * inv); b.z = f2bf(v1.z * inv); b.w = f2bf(v1.w * inv);
    *(s4v*)(zn + (long)row * DIM + t * 4) = a;
    *(s4v*)(zn + (long)row * DIM + 1024 + t * 4) = b;
}

// ---- 5. fused split-K sum + loss: one block per row i. Thread t owns cols
// t and t+256: sums the 8 partials in registers (sim never materialized),
// then block-reduces neg, computes pos terms, atomicAdds the result. ----
__global__ __launch_bounds__(256) void loss_fused(const float* __restrict__ simp,
                                                  const int* __restrict__ rel,
                                                  float* __restrict__ out) {
    __shared__ float red[4], rts[4], rct[4];
    int i = blockIdx.x, t = threadIdx.x, lane = t & 63, wave = t >> 6;
    int reli = rel[i];
    float s0 = 0.f, s1 = 0.f;
#pragma unroll
    for (int z = 0; z < 8; ++z) {
        s0 += simp[(long)z * 131072 + i * 512 + t];
        s1 += simp[(long)z * 131072 + i * 512 + 256 + t];
    }
    float e0 = __expf(10.0f * s0);
    float e1 = __expf(10.0f * s1);
    int d = abs(reli - rel[t]);
    float neg = e1 + ((d > 2) ? e0 : 0.f);
#pragma unroll
    for (int m = 1; m < 64; m <<= 1) neg += __shfl_xor(neg, m);
    if (lane == 0) red[wave] = neg;
    __syncthreads();
    neg = red[0] + red[1] + red[2] + red[3];
    float ts = 0.f, cnt = 0.f;
    if (t != i && d <= 2) { ts = logf(e0 + neg) - 10.0f * s0; cnt = 1.f; }
#pragma unroll
    for (int m = 1; m < 64; m <<= 1) { ts += __shfl_xor(ts, m); cnt += __shfl_xor(cnt, m); }
    if (lane == 0) { rts[wave] = ts; rct[wave] = cnt; }
    __syncthreads();
    if (t == 0) {
        float T = rts[0] + rts[1] + rts[2] + rts[3];
        float C = rct[0] + rct[1] + rct[2] + rct[3];
        atomicAdd(&out[0], C > 0.f ? T / C : 0.f);
        atomicAdd(&out[1], C > 0.f ? 1.f : 0.f);
    }
}

extern "C" void kernel_launch(void* const* d_in, const int* in_sizes, int n_in,
                              void* d_out, int out_size, void* d_ws, size_t ws_size,
                              hipStream_t stream) {
    const float* z0    = (const float*)d_in[0];
    const float* z1    = (const float*)d_in[1];
    const int*   rel0  = (const int*)d_in[2];
    const float* W1    = (const float*)d_in[4];
    const float* b1    = (const float*)d_in[5];
    const float* gamma = (const float*)d_in[6];
    const float* beta  = (const float*)d_in[7];
    const float* W2    = (const float*)d_in[8];
    const float* b2    = (const float*)d_in[9];

    char* ws = (char*)d_ws;
    short* p_bf  = (short*)(ws);                         // 2 MB
    float* h     = (float*)(ws + (2l  << 20));           // 4 MB
    short* hn    = (short*)(ws + (6l  << 20));           // 2 MB
    float* zproj = (float*)(ws + (8l  << 20));           // 4 MB
    short* zn    = (short*)(ws + (12l << 20));           // 2 MB
    float* simp  = (float*)(ws + (14l << 20));           // 4 MB (8 x 512 KB)
    float* stats = (float*)(ws + (19l << 20));           // 16 KB (sum | sumsq)
    short* w1h   = (short*)(ws + (20l << 20));           // 8 MB bf16 W1
    short* w2h   = (short*)(ws + (28l << 20));           // 8 MB bf16 W2
    bool castok = ws_size >= (36l << 20);

    if (castok) {
        pool_cast<<<12288, 256, 0, stream>>>(z0, z1, W1, W2, p_bf, w1h, w2h, stats);
    } else {
        hipMemsetAsync(stats, 0, 16384, stream);
        pool_cast<<<8192, 256, 0, stream>>>(z0, z1, nullptr, nullptr, p_bf,
                                            nullptr, nullptr, nullptr);
    }
    gemm_ks<<<dim3(32, 8, 1), 256, 0, stream>>>(p_bf, castok ? w1h : nullptr,
                                                castok ? nullptr : W1, b1, h, stats,
                                                NROW, DIM, DIM, DIM);
    bn_relu_cast<<<1024, 256, 0, stream>>>(h, stats, gamma, beta, hn);
    gemm_ks<<<dim3(32, 8, 1), 256, 0, stream>>>(hn, castok ? w2h : nullptr,
                                                castok ? nullptr : W2, b2, zproj, nullptr,
                                                NROW, DIM, DIM, DIM);
    rownorm<<<512, 256, 0, stream>>>(zproj, zn, (float*)d_out);
    gemm_ks<<<dim3(8, 4, 8), 256, 0, stream>>>(zn, zn, nullptr, nullptr, simp, nullptr,
                                               NB, NROW, DIM, 256);
    loss_fused<<<NB, 256, 0, stream>>>(simp, rel0, (float*)d_out);
}

// Round 4
// 331.043 us; speedup vs baseline: 1.1263x; 1.0182x over previous
//
#include <hip/hip_runtime.h>

typedef __attribute__((ext_vector_type(8))) short s8v;
typedef __attribute__((ext_vector_type(4))) short s4v;
typedef __attribute__((ext_vector_type(4))) float f4v;

#define DIM 2048
#define NROW 512   // 2*B
#define NB 256     // B

__device__ inline short f2bf(float f) {
    union { float f; unsigned int u; } v; v.f = f;
    unsigned int u = v.u;
    unsigned int r = (u + 0x7fffu + ((u >> 16) & 1u)) >> 16;
    return (short)r;
}

// pack two floats -> two truncated bf16 in one int (v_perm_b32).
__device__ __forceinline__ int pk_trunc(float a, float b) {
    return __builtin_amdgcn_perm(__float_as_uint(b), __float_as_uint(a), 0x07060302);
}

// sum across a quad of lanes via DPP quad_perm (VALU only, no LDS pipe)
__device__ __forceinline__ float qsum(float s) {
    int i = __float_as_int(s);
    s += __int_as_float(__builtin_amdgcn_update_dpp(i, i, 0xB1, 0xF, 0xF, false)); // [1,0,3,2]
    i = __float_as_int(s);
    s += __int_as_float(__builtin_amdgcn_update_dpp(i, i, 0x4E, 0xF, 0xF, false)); // [2,3,0,1]
    return s;
}

// ---- 1. fused: spatial mean pool (nt stream) + W1/W2 fp32->bf16 cast + stats zero ----
__global__ __launch_bounds__(256) void pool_cast(const float* __restrict__ z0,
                                                 const float* __restrict__ z1,
                                                 const float* __restrict__ W1,
                                                 const float* __restrict__ W2,
                                                 short* __restrict__ p,
                                                 short* __restrict__ w1h,
                                                 short* __restrict__ w2h,
                                                 float* __restrict__ stats) {
    int t = threadIdx.x;
    int c = blockIdx.x;
    if (c < 8192) {
        const float* src = (c < 4096) ? z0 + (long)c * 8192 : z1 + (long)(c - 4096) * 8192;
        int g = t >> 2, sub = t & 3;       // 64 groups x 4 lanes; group g owns pairs 2g,2g+1
        const float* base = src + g * 128 + sub * 4;
        f4v v[8];
#pragma unroll
        for (int j = 0; j < 8; ++j) v[j] = __builtin_nontemporal_load((const f4v*)(base + j * 16));
        __builtin_amdgcn_sched_barrier(0);  // keep all 8 loads issued before the reduce
        float sA = 0.f, sB = 0.f;
#pragma unroll
        for (int j = 0; j < 4; ++j) sA += v[j].x + v[j].y + v[j].z + v[j].w;
#pragma unroll
        for (int j = 4; j < 8; ++j) sB += v[j].x + v[j].y + v[j].z + v[j].w;
        sA = qsum(sA);
        sB = qsum(sB);
        if (sub == 0) {
            int pk = (int)(unsigned short)f2bf(sA * (1.0f / 64.0f))
                   | ((int)(unsigned short)f2bf(sB * (1.0f / 64.0f)) << 16);
            ((int*)p)[c * 64 + g] = pk;
        }
    } else {
        int cc = c - 8192;                  // 0..4095: 2048 slabs per W
        const float* w = (cc < 2048) ? W1 : W2;
        short* o = (cc < 2048) ? w1h : w2h;
        int idx = (cc & 2047) * 2048 + t * 8;
        f4v x = __builtin_nontemporal_load((const f4v*)(w + idx));
        f4v y = __builtin_nontemporal_load((const f4v*)(w + idx + 4));
        int4 o4;
        o4.x = pk_trunc(x.x, x.y);
        o4.y = pk_trunc(x.z, x.w);
        o4.z = pk_trunc(y.x, y.y);
        o4.w = pk_trunc(y.z, y.w);
        *(int4*)(o + idx) = o4;
        if (cc == 0) {                      // zero 4096-float stats buffer
#pragma unroll
            for (int k = 0; k < 16; ++k) stats[t + k * 256] = 0.f;
        }
    }
}

// XOR-swizzled LDS address (shorts), stride 256 (BK=256 legacy kernel).
__device__ __forceinline__ int swz(int r, int k) { return r * 256 + (k ^ ((r & 7) << 3)); }
// XOR-swizzled LDS address (shorts), stride 128 (BK=128 double-buffered kernel).
__device__ __forceinline__ int swz2(int r, int k) { return r * 128 + (k ^ ((r & 7) << 3)); }

// ---- 2. bf16 NT GEMM, double-buffered 2-phase (T14 async-stage) ----
// 64x64 tile, BK=128, 4 waves split K (32 each), LDS reduce. Per iter:
// issue next-tile global loads to regs -> ds_read+MFMA current buf ->
// vmcnt-drain + ds_write regs to other buf -> one barrier. Load latency
// hides under the MFMA phase (1 block/CU: no TLP to hide it otherwise).
__global__ __launch_bounds__(256, 1) void gemm_db(const short* __restrict__ A,
                                                  const short* __restrict__ B,
                                                  const float* __restrict__ bias,
                                                  float* __restrict__ C,
                                                  float* __restrict__ stats,
                                                  int M, int N, int K, int kChunk) {
    __shared__ short sm[2][16384];       // [buf][A(8192) | B(8192)] shorts = 64 KB
    int t = threadIdx.x;
    int n0 = blockIdx.x * 64, m0 = blockIdx.y * 64;
    int kbase = blockIdx.z * kChunk;
    long zoff = (long)blockIdx.z * M * N;
    int lane = t & 63, w = t >> 6;
    int l16 = lane & 15, quad = lane >> 4;
    int ks = w * 32;                     // this wave's K-slice inside BK=128
    f4v acc[4][4] = {};
    int srow = t >> 4;                   // 0..15 staging row (16 rows/pass)
    int skoff = (t & 15) * 8;            // 0..120 staging k-offset
    const short* aBase = &A[(long)(m0 + srow) * K + skoff];
    const short* bBase = &B[(long)(n0 + srow) * K + skoff];
    long rstride = (long)16 * K;
    int nIter = kChunk >> 7;
    s8v ra[4], rb[4];

    // prologue: stage tile 0 into buf 0
#pragma unroll
    for (int pp = 0; pp < 4; ++pp) ra[pp] = *(const s8v*)(aBase + pp * rstride + kbase);
#pragma unroll
    for (int pp = 0; pp < 4; ++pp) rb[pp] = *(const s8v*)(bBase + pp * rstride + kbase);
#pragma unroll
    for (int pp = 0; pp < 4; ++pp) *(s8v*)&sm[0][swz2(srow + pp * 16, skoff)] = ra[pp];
#pragma unroll
    for (int pp = 0; pp < 4; ++pp) *(s8v*)&sm[0][8192 + swz2(srow + pp * 16, skoff)] = rb[pp];
    __syncthreads();

    for (int it = 0; it < nIter; ++it) {
        int cur = it & 1;
        bool pf = (it + 1) < nIter;
        if (pf) {
            int k0 = kbase + (it + 1) * 128;
#pragma unroll
            for (int pp = 0; pp < 4; ++pp) ra[pp] = *(const s8v*)(aBase + pp * rstride + k0);
#pragma unroll
            for (int pp = 0; pp < 4; ++pp) rb[pp] = *(const s8v*)(bBase + pp * rstride + k0);
        }
        __builtin_amdgcn_sched_barrier(0);   // pin prefetch issue before the MFMA phase
        const short* lA = sm[cur];
        const short* lB = sm[cur] + 8192;
        s8v af[4], bf[4];
#pragma unroll
        for (int i = 0; i < 4; ++i)
            af[i] = *(const s8v*)&lA[swz2(i * 16 + l16, ks + quad * 8)];
#pragma unroll
        for (int j = 0; j < 4; ++j)
            bf[j] = *(const s8v*)&lB[swz2(j * 16 + l16, ks + quad * 8)];
#pragma unroll
        for (int i = 0; i < 4; ++i)
#pragma unroll
            for (int j = 0; j < 4; ++j)
                acc[i][j] = __builtin_amdgcn_mfma_f32_16x16x32_bf16(af[i], bf[j], acc[i][j], 0, 0, 0);
        if (pf) {
            int nb = cur ^ 1;
#pragma unroll
            for (int pp = 0; pp < 4; ++pp) *(s8v*)&sm[nb][swz2(srow + pp * 16, skoff)] = ra[pp];
#pragma unroll
            for (int pp = 0; pp < 4; ++pp) *(s8v*)&sm[nb][8192 + swz2(srow + pp * 16, skoff)] = rb[pp];
        }
        __syncthreads();
    }

    // cross-wave K reduction: each wave dumps 64x64 fp32 partial (fr aliases
    // both staging buffers: 4 waves x 4096 floats = 64 KB), then thread t
    // finalizes col c = t&63, rows (t>>6)*16 .. +16.
    float* fr = (float*)sm;
#pragma unroll
    for (int i = 0; i < 4; ++i)
#pragma unroll
        for (int j = 0; j < 4; ++j)
#pragma unroll
            for (int r = 0; r < 4; ++r)
                fr[w * 4096 + (i * 16 + quad * 4 + r) * 64 + j * 16 + l16] = acc[i][j][r];
    __syncthreads();
    int c = t & 63;
    int rbase = (t >> 6) * 16;
    float bv = bias ? bias[n0 + c] : 0.0f;
    float s = 0.f, q = 0.f;
#pragma unroll
    for (int r = 0; r < 16; ++r) {
        int rr = rbase + r;
        float h = fr[rr * 64 + c] + fr[4096 + rr * 64 + c]
                + fr[8192 + rr * 64 + c] + fr[12288 + rr * 64 + c] + bv;
        C[zoff + (long)(m0 + rr) * N + n0 + c] = h;
        s += h; q += h * h;
    }
    if (stats) {
        __syncthreads();
        fr[(t >> 6) * 64 + c] = s;
        fr[256 + (t >> 6) * 64 + c] = q;
        __syncthreads();
        if (t < 64) {
            float ss = fr[t] + fr[64 + t] + fr[128 + t] + fr[192 + t];
            float qq = fr[256 + t] + fr[320 + t] + fr[384 + t] + fr[448 + t];
            atomicAdd(&stats[n0 + t], ss);
            atomicAdd(&stats[2048 + n0 + t], qq);
        }
    }
}

// ---- 2b. legacy single-buffered GEMM (fp32-B capable) — small-ws fallback ----
__global__ __launch_bounds__(256) void gemm_ks(const short* __restrict__ A,
                                               const short* __restrict__ Bh,
                                               const float* __restrict__ Bf,
                                               const float* __restrict__ bias,
                                               float* __restrict__ C,
                                               float* __restrict__ stats,
                                               int M, int N, int K, int kChunk) {
    __shared__ short sm[2 * 64 * 256];   // 64 KB; aliased as fp32 for reduce
    short* lA = sm;
    short* lB = sm + 64 * 256;
    int t = threadIdx.x;
    int n0 = blockIdx.x * 64, m0 = blockIdx.y * 64;
    int kbase = blockIdx.z * kChunk;
    long zoff = (long)blockIdx.z * M * N;
    int lane = t & 63, w = t >> 6;
    int l16 = lane & 15, quad = lane >> 4;
    int ks = w * 64;
    f4v acc[4][4] = {};
    int sr = t >> 3;
    int sq8 = (t & 7) * 8;

    for (int it = 0; it < kChunk; it += 256) {
        int k0 = kbase + it;
#pragma unroll
        for (int pp = 0; pp < 2; ++pp) {
            int r = sr + pp * 32;
            const short* as = &A[(long)(m0 + r) * K + k0];
#pragma unroll
            for (int j = 0; j < 4; ++j)
                *(s8v*)&lA[swz(r, sq8 + j * 64)] = *(const s8v*)&as[sq8 + j * 64];
        }
        if (Bh) {
#pragma unroll
            for (int pp = 0; pp < 2; ++pp) {
                int r = sr + pp * 32;
                const short* bs = &Bh[(long)(n0 + r) * K + k0];
#pragma unroll
                for (int j = 0; j < 4; ++j)
                    *(s8v*)&lB[swz(r, sq8 + j * 64)] = *(const s8v*)&bs[sq8 + j * 64];
            }
        } else {
#pragma unroll
            for (int pp = 0; pp < 2; ++pp) {
                int r = sr + pp * 32;
                const float* bs = &Bf[(long)(n0 + r) * K + k0];
#pragma unroll
                for (int j = 0; j < 4; ++j) {
                    float4 x = *(const float4*)&bs[sq8 + j * 64];
                    float4 y = *(const float4*)&bs[sq8 + j * 64 + 4];
                    int4 o;
                    o.x = pk_trunc(x.x, x.y);
                    o.y = pk_trunc(x.z, x.w);
                    o.z = pk_trunc(y.x, y.y);
                    o.w = pk_trunc(y.z, y.w);
                    *(int4*)&lB[swz(r, sq8 + j * 64)] = o;
                }
            }
        }
        __syncthreads();
#pragma unroll
        for (int kk = 0; kk < 2; ++kk) {
            s8v af[4], bf[4];
#pragma unroll
            for (int i = 0; i < 4; ++i)
                af[i] = *(const s8v*)&lA[swz(i * 16 + l16, ks + kk * 32 + quad * 8)];
#pragma unroll
            for (int j = 0; j < 4; ++j)
                bf[j] = *(const s8v*)&lB[swz(j * 16 + l16, ks + kk * 32 + quad * 8)];
#pragma unroll
            for (int i = 0; i < 4; ++i)
#pragma unroll
                for (int j = 0; j < 4; ++j)
                    acc[i][j] = __builtin_amdgcn_mfma_f32_16x16x32_bf16(af[i], bf[j], acc[i][j], 0, 0, 0);
        }
        __syncthreads();
    }

    float* fr = (float*)sm;
#pragma unroll
    for (int i = 0; i < 4; ++i)
#pragma unroll
        for (int j = 0; j < 4; ++j)
#pragma unroll
            for (int r = 0; r < 4; ++r)
                fr[w * 4096 + (i * 16 + quad * 4 + r) * 64 + j * 16 + l16] = acc[i][j][r];
    __syncthreads();
    int c = t & 63;
    int rbase = (t >> 6) * 16;
    float bv = bias ? bias[n0 + c] : 0.0f;
    float s = 0.f, q = 0.f;
#pragma unroll
    for (int r = 0; r < 16; ++r) {
        int rr = rbase + r;
        float h = fr[rr * 64 + c] + fr[4096 + rr * 64 + c]
                + fr[8192 + rr * 64 + c] + fr[12288 + rr * 64 + c] + bv;
        C[zoff + (long)(m0 + rr) * N + n0 + c] = h;
        s += h; q += h * h;
    }
    if (stats) {
        __syncthreads();
        fr[(t >> 6) * 64 + c] = s;
        fr[256 + (t >> 6) * 64 + c] = q;
        __syncthreads();
        if (t < 64) {
            float ss = fr[t] + fr[64 + t] + fr[128 + t] + fr[192 + t];
            float qq = fr[256 + t] + fr[320 + t] + fr[384 + t] + fr[448 + t];
            atomicAdd(&stats[n0 + t], ss);
            atomicAdd(&stats[2048 + n0 + t], qq);
        }
    }
}

// ---- 3. bn finalize+apply+relu+cast bf16 ----
__global__ __launch_bounds__(256) void bn_relu_cast(const float* __restrict__ h,
                                                    const float* __restrict__ stats,
                                                    const float* __restrict__ gamma,
                                                    const float* __restrict__ beta,
                                                    short* __restrict__ hn) {
    int idx = (blockIdx.x * 256 + threadIdx.x) * 4;
    int col = idx & (DIM - 1);
    float4 s0 = *(const float4*)(stats + col);
    float4 s1 = *(const float4*)(stats + 2048 + col);
    float4 g  = *(const float4*)(gamma + col);
    float4 bt = *(const float4*)(beta + col);
    float4 v  = *(const float4*)(h + idx);
    float mu, var, sc, sh;
    s4v o;
    mu = s0.x * (1.0f / NROW); var = s1.x * (1.0f / NROW) - mu * mu;
    sc = g.x * rsqrtf(var + 1e-5f); sh = bt.x - mu * sc;
    o.x = f2bf(fmaxf(v.x * sc + sh, 0.f));
    mu = s0.y * (1.0f / NROW); var = s1.y * (1.0f / NROW) - mu * mu;
    sc = g.y * rsqrtf(var + 1e-5f); sh = bt.y - mu * sc;
    o.y = f2bf(fmaxf(v.y * sc + sh, 0.f));
    mu = s0.z * (1.0f / NROW); var = s1.z * (1.0f / NROW) - mu * mu;
    sc = g.z * rsqrtf(var + 1e-5f); sh = bt.z - mu * sc;
    o.z = f2bf(fmaxf(v.z * sc + sh, 0.f));
    mu = s0.w * (1.0f / NROW); var = s1.w * (1.0f / NROW) - mu * mu;
    sc = g.w * rsqrtf(var + 1e-5f); sh = bt.w - mu * sc;
    o.w = f2bf(fmaxf(v.w * sc + sh, 0.f));
    *(s4v*)(hn + idx) = o;
}

// ---- 4. row L2 normalize + cast bf16; block 0 zeroes the loss accumulators ----
__global__ __launch_bounds__(256) void rownorm(const float* __restrict__ z,
                                               short* __restrict__ zn,
                                               float* __restrict__ out) {
    __shared__ float red[4];
    int row = blockIdx.x, t = threadIdx.x;
    if (row == 0 && t == 0) { out[0] = 0.f; out[1] = 0.f; }
    const float* zr = z + (long)row * DIM;
    float4 v0 = *(const float4*)(zr + t * 4);
    float4 v1 = *(const float4*)(zr + 1024 + t * 4);
    float ss = v0.x * v0.x + v0.y * v0.y + v0.z * v0.z + v0.w * v0.w
             + v1.x * v1.x + v1.y * v1.y + v1.z * v1.z + v1.w * v1.w;
#pragma unroll
    for (int m = 1; m < 64; m <<= 1) ss += __shfl_xor(ss, m);
    if ((t & 63) == 0) red[t >> 6] = ss;
    __syncthreads();
    float tot = red[0] + red[1] + red[2] + red[3];
    float inv = 1.0f / fmaxf(sqrtf(tot), 1e-8f);
    s4v a, b;
    a.x = f2bf(v0.x * inv); a.y = f2bf(v0.y * inv); a.z = f2bf(v0.z * inv); a.w = f2bf(v0.w * inv);
    b.x = f2bf(v1.x * inv); b.y = f2bf(v1.y * inv); b.z = f2bf(v1.z * inv); b.w = f2bf(v1.w * inv);
    *(s4v*)(zn + (long)row * DIM + t * 4) = a;
    *(s4v*)(zn + (long)row * DIM + 1024 + t * 4) = b;
}

// ---- 5. fused split-K sum + loss ----
__global__ __launch_bounds__(256) void loss_fused(const float* __restrict__ simp,
                                                  const int* __restrict__ rel,
                                                  float* __restrict__ out) {
    __shared__ float red[4], rts[4], rct[4];
    int i = blockIdx.x, t = threadIdx.x, lane = t & 63, wave = t >> 6;
    int reli = rel[i];
    float s0 = 0.f, s1 = 0.f;
#pragma unroll
    for (int z = 0; z < 8; ++z) {
        s0 += simp[(long)z * 131072 + i * 512 + t];
        s1 += simp[(long)z * 131072 + i * 512 + 256 + t];
    }
    float e0 = __expf(10.0f * s0);
    float e1 = __expf(10.0f * s1);
    int d = abs(reli - rel[t]);
    float neg = e1 + ((d > 2) ? e0 : 0.f);
#pragma unroll
    for (int m = 1; m < 64; m <<= 1) neg += __shfl_xor(neg, m);
    if (lane == 0) red[wave] = neg;
    __syncthreads();
    neg = red[0] + red[1] + red[2] + red[3];
    float ts = 0.f, cnt = 0.f;
    if (t != i && d <= 2) { ts = logf(e0 + neg) - 10.0f * s0; cnt = 1.f; }
#pragma unroll
    for (int m = 1; m < 64; m <<= 1) { ts += __shfl_xor(ts, m); cnt += __shfl_xor(cnt, m); }
    if (lane == 0) { rts[wave] = ts; rct[wave] = cnt; }
    __syncthreads();
    if (t == 0) {
        float T = rts[0] + rts[1] + rts[2] + rts[3];
        float C = rct[0] + rct[1] + rct[2] + rct[3];
        atomicAdd(&out[0], C > 0.f ? T / C : 0.f);
        atomicAdd(&out[1], C > 0.f ? 1.f : 0.f);
    }
}

extern "C" void kernel_launch(void* const* d_in, const int* in_sizes, int n_in,
                              void* d_out, int out_size, void* d_ws, size_t ws_size,
                              hipStream_t stream) {
    const float* z0    = (const float*)d_in[0];
    const float* z1    = (const float*)d_in[1];
    const int*   rel0  = (const int*)d_in[2];
    const float* W1    = (const float*)d_in[4];
    const float* b1    = (const float*)d_in[5];
    const float* gamma = (const float*)d_in[6];
    const float* beta  = (const float*)d_in[7];
    const float* W2    = (const float*)d_in[8];
    const float* b2    = (const float*)d_in[9];

    char* ws = (char*)d_ws;
    short* p_bf  = (short*)(ws);                         // 2 MB
    float* h     = (float*)(ws + (2l  << 20));           // 4 MB
    short* hn    = (short*)(ws + (6l  << 20));           // 2 MB
    float* zproj = (float*)(ws + (8l  << 20));           // 4 MB
    short* zn    = (short*)(ws + (12l << 20));           // 2 MB
    float* simp  = (float*)(ws + (14l << 20));           // 4 MB (8 x 512 KB)
    float* stats = (float*)(ws + (19l << 20));           // 16 KB (sum | sumsq)
    short* w1h   = (short*)(ws + (20l << 20));           // 8 MB bf16 W1
    short* w2h   = (short*)(ws + (28l << 20));           // 8 MB bf16 W2
    bool castok = ws_size >= (36l << 20);

    if (castok) {
        pool_cast<<<12288, 256, 0, stream>>>(z0, z1, W1, W2, p_bf, w1h, w2h, stats);
        gemm_db<<<dim3(32, 8, 1), 256, 0, stream>>>(p_bf, w1h, b1, h, stats,
                                                    NROW, DIM, DIM, DIM);
        bn_relu_cast<<<1024, 256, 0, stream>>>(h, stats, gamma, beta, hn);
        gemm_db<<<dim3(32, 8, 1), 256, 0, stream>>>(hn, w2h, b2, zproj, nullptr,
                                                    NROW, DIM, DIM, DIM);
        rownorm<<<512, 256, 0, stream>>>(zproj, zn, (float*)d_out);
        gemm_db<<<dim3(8, 4, 8), 256, 0, stream>>>(zn, zn, nullptr, simp, nullptr,
                                                   NB, NROW, DIM, 256);
        loss_fused<<<NB, 256, 0, stream>>>(simp, rel0, (float*)d_out);
    } else {
        hipMemsetAsync(stats, 0, 16384, stream);
        pool_cast<<<8192, 256, 0, stream>>>(z0, z1, nullptr, nullptr, p_bf,
                                            nullptr, nullptr, nullptr);
        gemm_ks<<<dim3(32, 8, 1), 256, 0, stream>>>(p_bf, nullptr, W1, b1, h, stats,
                                                    NROW, DIM, DIM, DIM);
        bn_relu_cast<<<1024, 256, 0, stream>>>(h, stats, gamma, beta, hn);
        gemm_ks<<<dim3(32, 8, 1), 256, 0, stream>>>(hn, nullptr, W2, b2, zproj, nullptr,
                                                    NROW, DIM, DIM, DIM);
        rownorm<<<512, 256, 0, stream>>>(zproj, zn, (float*)d_out);
        gemm_ks<<<dim3(8, 4, 8), 256, 0, stream>>>(zn, zn, nullptr, nullptr, simp, nullptr,
                                                   NB, NROW, DIM, 256);
        loss_fused<<<NB, 256, 0, stream>>>(simp, rel0, (float*)d_out);
    }
}